// Round 4
// baseline (2150.517 us; speedup 1.0000x reference)
//
#include <hip/hip_runtime.h>
#include <hip/hip_fp16.h>

// GCN 3-layer forward. R9 = phase-partitioned fused pulls:
//  - CSR rows partition-major (key = srcPart*512 + dstLocal), 512-node buckets,
//    fixed-cap slabs (k_hist/k_scan deleted), rowp8 = packed start|cnt per (node,part)
//  - pull kernels: LDS fp32 acc (512x16), 8 phases over 2MB table slices,
//    soft global barrier (locality-only, bounded spin) keeps GPU on one slice
//  - R8 lesson: acc must stay on-chip; slices must be << 4MB L2
// R7 baseline: pull1/2 FETCH 840MB (75% gather L2-miss), pull3 FETCH 495MB.

typedef unsigned int uint;
typedef unsigned short ushort;
typedef unsigned long long ull;

#define NBMAX 1024        // max buckets (dst >> 9), 512 nodes each
#define BKN 512
#define BCAP 17408        // bucketed slab cap per bucket (mean 16384, +8 sigma)
#define SCAP 20480        // srcS slab cap per bucket (mean ~18400, pads incl)
#define PT_THREADS 512
#define PT_TILE 8192      // 16 edges per thread
#define NPART 8           // src partitions (src>>16): 2MB fp16 table slices
#define BAR_STRIDE 528    // uints per barrier row (root + 32 spread counters)
#define BAR_LAYER (7 * BAR_STRIDE)

// ---- init: fixed slab cursors + barrier counters ----
__global__ void k_init(uint* __restrict__ gcur, uint* __restrict__ bars) {
    int t = threadIdx.x;                 // 1024 threads, 1 block
    gcur[t] = (uint)t * BCAP;
    for (int i = t; i < 3 * BAR_LAYER; i += 1024) bars[i] = 0;
}

// ---- LDS-staged partition: edges -> bucketed (packed src | dstLocal<<19) ----
__global__ __launch_bounds__(PT_THREADS) void k_part(const int* __restrict__ src,
                                                     const int* __restrict__ dst, int E,
                                                     uint* __restrict__ gcur,
                                                     uint* __restrict__ bucketed) {
    __shared__ uint stage[PT_TILE];
    __shared__ ushort sbuck[PT_TILE];
    __shared__ uint hist[NBMAX], lofs[NBMAX], base[NBMAX];
    __shared__ uint tsum[PT_THREADS];
    int t = threadIdx.x;
    long long start = (long long)blockIdx.x * PT_TILE;
    int cnt = (int)min((long long)PT_TILE, (long long)E - start);

    hist[2 * t] = 0; hist[2 * t + 1] = 0;
    __syncthreads();
    uint myb[16], myr[16], mys[16];
#pragma unroll
    for (int k = 0; k < 16; ++k) {
        int idx = t + k * PT_THREADS;
        if (idx < cnt) {
            uint d = (uint)dst[start + idx];
            uint s = (uint)src[start + idx];
            uint b = d >> 9;
            myb[k] = b;
            mys[k] = s | ((d & 511u) << 19);
            myr[k] = atomicAdd(&hist[b], 1u);
        }
    }
    __syncthreads();
    uint h0 = hist[2 * t], h1 = hist[2 * t + 1];
    tsum[t] = h0 + h1;
    __syncthreads();
    for (int off = 1; off < PT_THREADS; off <<= 1) {
        uint x = (t >= off) ? tsum[t - off] : 0u;
        __syncthreads();
        tsum[t] += x;
        __syncthreads();
    }
    uint ex = tsum[t] - (h0 + h1);
    lofs[2 * t] = ex;
    lofs[2 * t + 1] = ex + h0;
    if (h0) base[2 * t] = atomicAdd(&gcur[2 * t], h0);
    if (h1) base[2 * t + 1] = atomicAdd(&gcur[2 * t + 1], h1);
    __syncthreads();
#pragma unroll
    for (int k = 0; k < 16; ++k) {
        int idx = t + k * PT_THREADS;
        if (idx < cnt) {
            uint pos = lofs[myb[k]] + myr[k];
            stage[pos] = mys[k];
            sbuck[pos] = (ushort)myb[k];
        }
    }
    __syncthreads();
#pragma unroll
    for (int k = 0; k < 16; ++k) {
        int idx = t + k * PT_THREADS;
        if (idx < cnt) {
            uint b = sbuck[idx];
            uint pos = base[b] + ((uint)idx - lofs[b]);
            if (pos < (uint)(b + 1) * BCAP) bucketed[pos] = stage[idx];  // ~always
        }
    }
}

// ---- per-bucket CSR: counting sort keyed (srcPart*512 + dstLocal), pad-to-2 ----
// rowp8[node*8+p] = (slabStart+segStart) | (cnt<<25); pad slot = sentinel N.
__global__ __launch_bounds__(512) void k_csr(const uint* __restrict__ bucketed,
                                             const uint* __restrict__ gcur,
                                             uint* __restrict__ rowp8,
                                             float* __restrict__ dis,
                                             int* __restrict__ srcS, int N) {
    __shared__ uint c[BKN * NPART];        // counts -> cursors (reused)
    __shared__ uint tsum[512];
    __shared__ __align__(16) int stage[SCAP];
    int b = blockIdx.x, t = threadIdx.x;
    uint beg = (uint)b * BCAP;
    uint end = min(gcur[b], (uint)(b + 1) * BCAP);
    for (int i = t; i < BKN * NPART; i += 512) c[i] = 0;
    __syncthreads();
    for (uint e = beg + t; e < end; e += 512) {
        uint v = bucketed[e];
        uint key = (((v & 0x7ffffu) >> 16) << 9) | (v >> 19);
        atomicAdd(&c[key], 1u);
    }
    __syncthreads();
    // degree -> dis (before counts become cursors)
    {
        int node = (b << 9) + t;
        if (node < N) {
            uint deg = 0;
#pragma unroll
            for (int p = 0; p < NPART; ++p) deg += c[(p << 9) | t];
            dis[node] = rsqrtf((float)(deg + 1u));   // +1 self-loop
        }
    }
    // thread t owns keys 8t..8t+7 (one partition, 8 consecutive locals)
    uint cnt[8], pad[8], ps = 0;
#pragma unroll
    for (int i = 0; i < 8; ++i) {
        cnt[i] = c[t * 8 + i];
        pad[i] = (cnt[i] + 1u) & ~1u;
        ps += pad[i];
    }
    __syncthreads();
    tsum[t] = ps;
    __syncthreads();
    for (int off = 1; off < 512; off <<= 1) {
        uint x = (t >= off) ? tsum[t - off] : 0u;
        __syncthreads();
        tsum[t] += x;
        __syncthreads();
    }
    uint tot = tsum[511];
    uint kb = tsum[t] - ps;
    uint slab = (uint)b * SCAP;
    int p = t >> 6, local0 = (t & 63) << 3;
    uint run = kb;
#pragma unroll
    for (int i = 0; i < 8; ++i) {
        uint st = run;
        rowp8[(size_t)((b << 9) + local0 + i) * 8 + p] = (slab + st) | (cnt[i] << 25);
        c[t * 8 + i] = st;                  // cursor, slab-relative
        if (cnt[i] & 1u) {
            uint idx = st + cnt[i];
            if (idx < (uint)SCAP) stage[idx] = N;
            else srcS[slab + idx] = N;      // ~never (spill)
        }
        run += pad[i];
    }
    __syncthreads();
    for (uint e = beg + t; e < end; e += 512) {
        uint v = bucketed[e];
        uint s = v & 0x7ffffu;
        uint key = ((s >> 16) << 9) | (v >> 19);
        uint idx = atomicAdd(&c[key], 1u);
        if (idx < (uint)SCAP) stage[idx] = (int)s;
        else srcS[slab + idx] = (int)s;     // ~never (spill)
    }
    __syncthreads();
    uint capped = min(tot, (uint)SCAP);
    uint cap4 = capped & ~3u;
    for (uint i = t * 4; i < cap4; i += 512 * 4)
        *(int4*)(srcS + slab + i) = *(const int4*)(stage + i);
    if (t < (int)(capped & 3u)) srcS[slab + cap4 + t] = stage[cap4 + t];
}

// ---- layer-1: A'[i,0:15] = (x[i,:]@W1) * dis[i] -> fp16, A'[i,15]=0 ----
__global__ void k_lin_first(const float* __restrict__ x, const float* __restrict__ W,
                            const float* __restrict__ dis, __half* __restrict__ A, int N) {
    int i = blockIdx.x * blockDim.x + threadIdx.x;
    if (i >= N) return;
    float in[15];
#pragma unroll
    for (int j = 0; j < 15; ++j) in[j] = x[i * 15 + j];
    float di = dis[i];
#pragma unroll
    for (int o = 0; o < 15; ++o) {
        float acc = 0.f;
#pragma unroll
        for (int j = 0; j < 15; ++j) acc = fmaf(in[j], W[j * 15 + o], acc);
        A[i * 16 + o] = __float2half(acc * di);
    }
    A[i * 16 + 15] = __float2half(0.f);
}

// ---- soft global barrier: locality pacing only (no correctness dependence) ----
__device__ __forceinline__ void softbar(uint* __restrict__ bars, int phase, int nblk) {
    __syncthreads();
    if (threadIdx.x == 0) {
        uint* row = bars + phase * BAR_STRIDE;
        uint ngroups = ((uint)nblk + 31u) >> 5;
        uint g = (uint)blockIdx.x >> 5;
        uint gsz = min(32u, (uint)nblk - g * 32u);
        uint prev = atomicAdd(&row[16 + g * 16], 1u);   // spread counters, own line
        if (prev + 1u == gsz) atomicAdd(&row[0], 1u);
        int spins = 0;
        while (spins < 2000) {
            uint v = __hip_atomic_load(&row[0], __ATOMIC_RELAXED,
                                       __HIP_MEMORY_SCOPE_AGENT);
            if (v >= ngroups) break;
            __builtin_amdgcn_s_sleep(8);
            ++spins;
        }
    }
    __syncthreads();
}

// ---- phased pull: block = bucket (512 nodes), LDS fp32 acc, 8 slice phases ----
// L=1: Ap->relu@W2->Bp  L=2: Bp->relu@W3->Cp  L=3: Cp->out fp32
template <int L>
__global__ __launch_bounds__(256, 4) void k_pull_ph(
    const __half* __restrict__ tab, const int* __restrict__ srcS,
    const uint* __restrict__ rowp8, const float* __restrict__ dis,
    const float* __restrict__ Wm, const float* __restrict__ bias,
    void* __restrict__ outp, uint* __restrict__ bars, int nblk, int N) {
    constexpr int TW = (L == 3) ? 4 : 16;        // table row width (halves)
    constexpr int GROUPS = 256 / TW;             // node-groups per block
    constexpr int ITERS = BKN / GROUPS;
    __shared__ float accl[BKN * TW];
    __shared__ float wl[232];
    int t = threadIdx.x;
    int nb = blockIdx.x << 9;
    int j = t & (TW - 1);
    int g = t / TW;
    if constexpr (L == 1) { for (int i = t; i < 225; i += 256) wl[i] = Wm[i]; }
    if constexpr (L == 2) { for (int i = t; i < 60; i += 256) wl[i] = Wm[i]; }
    // self term (pre-scaled rows, block-local contiguous reads)
#pragma unroll
    for (int it = 0; it < ITERS; ++it) {
        int ln = it * GROUPS + g;
        int node = nb + ln;
        accl[ln * TW + j] = (node < N) ? __half2float(tab[(size_t)node * TW + j]) : 0.f;
    }
    for (int p = 0; p < NPART; ++p) {
        for (int it = 0; it < ITERS; ++it) {
            int ln = it * GROUPS + g;
            int node = nb + ln;
            if (node < N) {
                uint rv = rowp8[(size_t)node * 8 + p];
                uint cnt = rv >> 25;
                if (cnt) {
                    uint beg = rv & 0x1ffffffu;
                    uint end2 = beg + ((cnt + 1u) & ~1u);
                    float a = 0.f;
                    for (uint e = beg; e < end2; e += 2) {
                        ull w = __builtin_nontemporal_load((const ull*)(srcS + e));
                        int s0 = (int)(uint)(w & 0xffffffffull);
                        int s1 = (int)(uint)(w >> 32);
                        a += __half2float(tab[(size_t)s0 * TW + j])
                           + __half2float(tab[(size_t)s1 * TW + j]);
                    }
                    accl[ln * TW + j] += a;
                }
            }
        }
        if (p < NPART - 1) softbar(bars, p, nblk);
    }
    __syncthreads();
    // epilogue
    for (int it = 0; it < ITERS; ++it) {
        int ln = it * GROUPS + g;
        int node = nb + ln;
        if (node >= N) continue;
        float di = dis[node];
        if constexpr (L == 3) {
            ((float*)outp)[(size_t)node * 4 + j] = accl[ln * 4 + j] * di + bias[j];
        } else {
            float a = accl[ln * 16 + j];
            float bj = bias[j < 15 ? j : 0];
            float val = (j < 15) ? fmaxf(a * di + bj, 0.f) : 0.f;
            accl[ln * 16 + j] = val;        // same-wave LDS exchange within group
            if constexpr (L == 1) {
                float o = 0.f;
                if (j < 15) {
#pragma unroll
                    for (int k = 0; k < 15; ++k)
                        o = fmaf(accl[ln * 16 + k], wl[k * 15 + j], o);
                }
                ((__half*)outp)[(size_t)node * 16 + j] =
                    __float2half((j < 15 ? o : 0.f) * di);
            } else {
                if (j < 4) {
                    float o = 0.f;
#pragma unroll
                    for (int k = 0; k < 15; ++k)
                        o = fmaf(accl[ln * 16 + k], wl[k * 4 + j], o);
                    ((__half*)outp)[(size_t)node * 4 + j] = __float2half(o * di);
                }
            }
        }
    }
}

extern "C" void kernel_launch(void* const* d_in, const int* in_sizes, int n_in,
                              void* d_out, int out_size, void* d_ws, size_t ws_size,
                              hipStream_t stream) {
    const float* x  = (const float*)d_in[0];
    const int*   ei = (const int*)d_in[1];
    const float* W1 = (const float*)d_in[3];
    const float* b1 = (const float*)d_in[4];
    const float* W2 = (const float*)d_in[5];
    const float* b2 = (const float*)d_in[6];
    const float* W3 = (const float*)d_in[7];
    const float* b3 = (const float*)d_in[8];
    float* out = (float*)d_out;

    const int N = in_sizes[0] / 15;
    const int E = in_sizes[1] / 2;
    const int* src = ei;
    const int* dst = ei + E;
    const int NBr = (N + BKN - 1) / BKN;   // live buckets (977)

    char* ws = (char*)d_ws;
    auto align = [](size_t v) { return (v + 255) & ~(size_t)255; };
    size_t off = 0;
    uint* rowp8 = (uint*)(ws + off); off += align((size_t)NBMAX * BKN * 8 * 4);
    float* dis  = (float*)(ws + off); off += align((size_t)N * 4);
    uint* gcur  = (uint*)(ws + off); off += align((size_t)NBMAX * 4);
    uint* bars  = (uint*)(ws + off); off += align((size_t)3 * BAR_LAYER * 4);
    int*  srcS  = (int*)(ws + off);  off += align((size_t)NBMAX * SCAP * 4);
    // slabY: bucketed (71MB) dead after k_csr, overlaid by B'(fp16)+C'(fp16)
    char* slabY = ws + off;
    uint*   bucketed = (uint*)slabY;
    __half* Bp = (__half*)slabY;
    __half* Cp = (__half*)(slabY + align((size_t)(N + 1) * 16 * 2));
    off += align((size_t)NBMAX * BCAP * 4);
    __half* Ap = (__half*)(ws + off);  // (N+1) x 16 fp16

    const int nTiles = (E + PT_TILE - 1) / PT_TILE;
    const int nbN = (N + 255) / 256;

    // CSR build (partition-major rows, fixed slabs)
    k_init<<<1, 1024, 0, stream>>>(gcur, bars);
    k_part<<<nTiles, PT_THREADS, 0, stream>>>(src, dst, E, gcur, bucketed);
    k_csr<<<NBr, 512, 0, stream>>>(bucketed, gcur, rowp8, dis, srcS, N);
    // bucketed dead -> slabY becomes B'/C'

    k_lin_first<<<nbN, 256, 0, stream>>>(x, W1, dis, Ap, N);
    // sentinel zero-rows (row N) for pad gathers
    hipMemsetAsync(Ap + (size_t)N * 16, 0, 16 * 2, stream);
    hipMemsetAsync(Bp + (size_t)N * 16, 0, 16 * 2, stream);
    hipMemsetAsync(Cp + (size_t)N * 4, 0, 4 * 2, stream);

    k_pull_ph<1><<<NBr, 256, 0, stream>>>(Ap, srcS, rowp8, dis, W2, b1, Bp,
                                          bars + 0 * BAR_LAYER, NBr, N);
    k_pull_ph<2><<<NBr, 256, 0, stream>>>(Bp, srcS, rowp8, dis, W3, b2, Cp,
                                          bars + 1 * BAR_LAYER, NBr, N);
    k_pull_ph<3><<<NBr, 256, 0, stream>>>(Cp, srcS, rowp8, dis, nullptr, b3, out,
                                          bars + 2 * BAR_LAYER, NBr, N);
}

// Round 5
// 876.189 us; speedup vs baseline: 2.4544x; 2.4544x over previous
//
#include <hip/hip_runtime.h>
#include <hip/hip_fp16.h>

// GCN 3-layer forward. R10 = R9 locality (phases + softbar, CONFIRMED: FETCH
// 840->194MB) + R7-class parallelism (thread-per-node, register fp32 acc):
//  - k_pull_res: 489 blocks x 512 thr (all co-resident at 2 blk/CU), thread
//    owns 2 nodes, acc[16] fp32 in VGPRs, 8 phases over 2MB table slices
//  - CSR: pad-to-4 segments (one int4/segment mean), rowp8 part-major layout
//  - R9 failure was MLP structure (250k threads, sequential node walk), not
//    the barrier: restore ~8 independent gathers/thread/phase.

typedef unsigned int uint;
typedef unsigned short ushort;
typedef unsigned long long ull;

#define NBMAX 1024        // max buckets (dst >> 9), 512 nodes each
#define BKN 512
#define BCAP 17408        // bucketed slab cap per bucket (mean 16384, +8 sigma)
#define SCAP 24576        // srcS slab cap (mean ~22.4k padded, +16 sigma)
#define PT_THREADS 512
#define PT_TILE 8192      // 16 edges per thread
#define NPART 8           // src partitions (src>>16): 2MB fp16 table slices
#define BAR_STRIDE 528    // uints per barrier row (root + 32 spread counters)
#define BAR_LAYER (7 * BAR_STRIDE)

// ---- init: fixed slab cursors + barrier counters ----
__global__ void k_init(uint* __restrict__ gcur, uint* __restrict__ bars) {
    int t = threadIdx.x;                 // 1024 threads, 1 block
    gcur[t] = (uint)t * BCAP;
    for (int i = t; i < 3 * BAR_LAYER; i += 1024) bars[i] = 0;
}

// ---- LDS-staged partition: edges -> bucketed (packed src | dstLocal<<19) ----
__global__ __launch_bounds__(PT_THREADS) void k_part(const int* __restrict__ src,
                                                     const int* __restrict__ dst, int E,
                                                     uint* __restrict__ gcur,
                                                     uint* __restrict__ bucketed) {
    __shared__ uint stage[PT_TILE];
    __shared__ ushort sbuck[PT_TILE];
    __shared__ uint hist[NBMAX], lofs[NBMAX], base[NBMAX];
    __shared__ uint tsum[PT_THREADS];
    int t = threadIdx.x;
    long long start = (long long)blockIdx.x * PT_TILE;
    int cnt = (int)min((long long)PT_TILE, (long long)E - start);

    hist[2 * t] = 0; hist[2 * t + 1] = 0;
    __syncthreads();
    uint myb[16], myr[16], mys[16];
#pragma unroll
    for (int k = 0; k < 16; ++k) {
        int idx = t + k * PT_THREADS;
        if (idx < cnt) {
            uint d = (uint)dst[start + idx];
            uint s = (uint)src[start + idx];
            uint b = d >> 9;
            myb[k] = b;
            mys[k] = s | ((d & 511u) << 19);
            myr[k] = atomicAdd(&hist[b], 1u);
        }
    }
    __syncthreads();
    uint h0 = hist[2 * t], h1 = hist[2 * t + 1];
    tsum[t] = h0 + h1;
    __syncthreads();
    for (int off = 1; off < PT_THREADS; off <<= 1) {
        uint x = (t >= off) ? tsum[t - off] : 0u;
        __syncthreads();
        tsum[t] += x;
        __syncthreads();
    }
    uint ex = tsum[t] - (h0 + h1);
    lofs[2 * t] = ex;
    lofs[2 * t + 1] = ex + h0;
    if (h0) base[2 * t] = atomicAdd(&gcur[2 * t], h0);
    if (h1) base[2 * t + 1] = atomicAdd(&gcur[2 * t + 1], h1);
    __syncthreads();
#pragma unroll
    for (int k = 0; k < 16; ++k) {
        int idx = t + k * PT_THREADS;
        if (idx < cnt) {
            uint pos = lofs[myb[k]] + myr[k];
            stage[pos] = mys[k];
            sbuck[pos] = (ushort)myb[k];
        }
    }
    __syncthreads();
#pragma unroll
    for (int k = 0; k < 16; ++k) {
        int idx = t + k * PT_THREADS;
        if (idx < cnt) {
            uint b = sbuck[idx];
            uint pos = base[b] + ((uint)idx - lofs[b]);
            if (pos < (uint)(b + 1) * BCAP) bucketed[pos] = stage[idx];  // ~always
        }
    }
}

// ---- per-bucket CSR: counting sort keyed (srcPart*512 + dstLocal), pad-to-4 ----
// rowp8[(p<<19)+node] = (slabStart+segStart) | (cnt<<25); pad slots = sentinel N.
__global__ __launch_bounds__(512) void k_csr(const uint* __restrict__ bucketed,
                                             const uint* __restrict__ gcur,
                                             uint* __restrict__ rowp8,
                                             float* __restrict__ dis,
                                             int* __restrict__ srcS, int N) {
    __shared__ uint c[BKN * NPART];        // counts -> cursors (reused)
    __shared__ uint tsum[512];
    __shared__ __align__(16) int stage[SCAP];
    int b = blockIdx.x, t = threadIdx.x;
    uint beg = (uint)b * BCAP;
    uint end = min(gcur[b], (uint)(b + 1) * BCAP);
    for (int i = t; i < BKN * NPART; i += 512) c[i] = 0;
    __syncthreads();
    for (uint e = beg + t; e < end; e += 512) {
        uint v = bucketed[e];
        uint key = (((v & 0x7ffffu) >> 16) << 9) | (v >> 19);
        atomicAdd(&c[key], 1u);
    }
    __syncthreads();
    // degree -> dis (before counts become cursors)
    {
        int node = (b << 9) + t;
        if (node < N) {
            uint deg = 0;
#pragma unroll
            for (int p = 0; p < NPART; ++p) deg += c[(p << 9) | t];
            dis[node] = rsqrtf((float)(deg + 1u));   // +1 self-loop
        }
    }
    // thread t owns keys 8t..8t+7 (one partition p=t>>6, 8 consecutive locals)
    uint cnt[8], pad[8], ps = 0;
#pragma unroll
    for (int i = 0; i < 8; ++i) {
        cnt[i] = c[t * 8 + i];
        pad[i] = (cnt[i] + 3u) & ~3u;
        ps += pad[i];
    }
    __syncthreads();
    tsum[t] = ps;
    __syncthreads();
    for (int off = 1; off < 512; off <<= 1) {
        uint x = (t >= off) ? tsum[t - off] : 0u;
        __syncthreads();
        tsum[t] += x;
        __syncthreads();
    }
    uint tot = tsum[511];
    uint kb = tsum[t] - ps;
    uint slab = (uint)b * SCAP;
    int p = t >> 6, local0 = (t & 63) << 3;
    uint run = kb;
#pragma unroll
    for (int i = 0; i < 8; ++i) {
        uint st = run;
        rowp8[((uint)p << 19) + (uint)((b << 9) + local0 + i)] =
            (slab + st) | (cnt[i] << 25);
        c[t * 8 + i] = st;                  // cursor, slab-relative
        for (uint q = cnt[i]; q < pad[i]; ++q) {   // sentinel pads (<=3)
            uint idx = st + q;
            if (idx < (uint)SCAP) stage[idx] = N;
            else srcS[slab + idx] = N;      // ~never (spill)
        }
        run += pad[i];
    }
    __syncthreads();
    for (uint e = beg + t; e < end; e += 512) {
        uint v = bucketed[e];
        uint s = v & 0x7ffffu;
        uint key = ((s >> 16) << 9) | (v >> 19);
        uint idx = atomicAdd(&c[key], 1u);
        if (idx < (uint)SCAP) stage[idx] = (int)s;
        else srcS[slab + idx] = (int)s;     // ~never (spill)
    }
    __syncthreads();
    uint capped = min(tot, (uint)SCAP);
    uint cap4 = capped & ~3u;
    for (uint i = t * 4; i < cap4; i += 512 * 4)
        *(int4*)(srcS + slab + i) = *(const int4*)(stage + i);
    if (t < (int)(capped & 3u)) srcS[slab + cap4 + t] = stage[cap4 + t];
}

// ---- layer-1: A'[i,0:15] = (x[i,:]@W1) * dis[i] -> fp16, A'[i,15]=0 ----
__global__ void k_lin_first(const float* __restrict__ x, const float* __restrict__ W,
                            const float* __restrict__ dis, __half* __restrict__ A, int N) {
    int i = blockIdx.x * blockDim.x + threadIdx.x;
    if (i >= N) return;
    float in[15];
#pragma unroll
    for (int j = 0; j < 15; ++j) in[j] = x[i * 15 + j];
    float di = dis[i];
#pragma unroll
    for (int o = 0; o < 15; ++o) {
        float acc = 0.f;
#pragma unroll
        for (int j = 0; j < 15; ++j) acc = fmaf(in[j], W[j * 15 + o], acc);
        A[i * 16 + o] = __float2half(acc * di);
    }
    A[i * 16 + 15] = __float2half(0.f);
}

// ---- soft global barrier: locality pacing only (no correctness dependence) ----
__device__ __forceinline__ void softbar(uint* __restrict__ bars, int phase, int nblk) {
    __syncthreads();
    if (threadIdx.x == 0) {
        uint* row = bars + phase * BAR_STRIDE;
        uint ngroups = ((uint)nblk + 31u) >> 5;
        uint g = (uint)blockIdx.x >> 5;
        uint gsz = min(32u, (uint)nblk - g * 32u);
        uint prev = atomicAdd(&row[16 + g * 16], 1u);   // spread counters, own line
        if (prev + 1u == gsz) atomicAdd(&row[0], 1u);
        int spins = 0;
        while (spins < 2000) {
            uint v = __hip_atomic_load(&row[0], __ATOMIC_RELAXED,
                                       __HIP_MEMORY_SCOPE_AGENT);
            if (v >= ngroups) break;
            __builtin_amdgcn_s_sleep(8);
            ++spins;
        }
    }
    __syncthreads();
}

template <int TW>
__device__ __forceinline__ void load_row(const __half* __restrict__ tab, int node,
                                         float (&acc)[TW]) {
    const __half2* r = (const __half2*)(tab + (size_t)node * TW);
#pragma unroll
    for (int h = 0; h < TW / 2; ++h) {
        float2 f = __half22float2(r[h]);
        acc[2 * h] = f.x;
        acc[2 * h + 1] = f.y;
    }
}

template <int TW>
__device__ __forceinline__ void gather_seg(const __half* __restrict__ tab,
                                           const int* __restrict__ srcS,
                                           uint rv, float (&acc)[TW]) {
    uint cnt = rv >> 25;
    if (!cnt) return;
    uint e = rv & 0x1ffffffu;
    uint end4 = e + ((cnt + 3u) & ~3u);
    for (; e < end4; e += 4) {
        int4 s4 = *(const int4*)(srcS + e);     // 16B-aligned segment
        const __half2* r0 = (const __half2*)(tab + (size_t)s4.x * TW);
        const __half2* r1 = (const __half2*)(tab + (size_t)s4.y * TW);
        const __half2* r2 = (const __half2*)(tab + (size_t)s4.z * TW);
        const __half2* r3 = (const __half2*)(tab + (size_t)s4.w * TW);
#pragma unroll
        for (int h = 0; h < TW / 2; ++h) {
            float2 f0 = __half22float2(r0[h]);
            float2 f1 = __half22float2(r1[h]);
            float2 f2 = __half22float2(r2[h]);
            float2 f3 = __half22float2(r3[h]);
            acc[2 * h] += (f0.x + f1.x) + (f2.x + f3.x);
            acc[2 * h + 1] += (f0.y + f1.y) + (f2.y + f3.y);
        }
    }
}

// ---- resident phased pull: thread owns 2 nodes, register acc, 8 phases ----
// L=1: Ap->relu@W2->Bp  L=2: Bp->relu@W3->Cp  L=3: Cp->out fp32
template <int L>
__global__ __launch_bounds__(512, 4) void k_pull_res(
    const __half* __restrict__ tab, const int* __restrict__ srcS,
    const uint* __restrict__ rowp8, const float* __restrict__ dis,
    const float* __restrict__ Wm, const float* __restrict__ bias,
    void* __restrict__ outp, uint* __restrict__ bars, int nblk, int N) {
    constexpr int TW = (L == 3) ? 4 : 16;
    __shared__ float wl[240];
    int t = threadIdx.x;
    int n0 = (blockIdx.x << 10) + t;
    int n1 = n0 + 512;
    if constexpr (L == 1) {
        for (int i = t; i < 225; i += 512) wl[i] = Wm[i];
        if (t < 15) wl[225 + t] = bias[t];
    }
    if constexpr (L == 2) {
        for (int i = t; i < 60; i += 512) wl[i] = Wm[i];
        if (t < 15) wl[60 + t] = bias[t];
    }
    if constexpr (L == 3) {
        if (t < 4) wl[t] = bias[t];
    }
    __syncthreads();
    bool v0 = n0 < N, v1 = n1 < N;
    float a0[TW], a1[TW];
    if (v0) load_row<TW>(tab, n0, a0);
    if (v1) load_row<TW>(tab, n1, a1);
    for (int p = 0; p < NPART; ++p) {
        uint base = (uint)p << 19;
        if (v0) gather_seg<TW>(tab, srcS, rowp8[base + (uint)n0], a0);
        if (v1) gather_seg<TW>(tab, srcS, rowp8[base + (uint)n1], a1);
        if (p < NPART - 1) softbar(bars, p, nblk);
    }
    // epilogue (per node, all-register MLP)
#pragma unroll
    for (int nn = 0; nn < 2; ++nn) {
        int node = nn ? n1 : n0;
        if (node >= N) continue;
        float* a = nn ? a1 : a0;
        float di = dis[node];
        if constexpr (L == 3) {
            float4 o;
            o.x = a[0] * di + wl[0];
            o.y = a[1] * di + wl[1];
            o.z = a[2] * di + wl[2];
            o.w = a[3] * di + wl[3];
            *(float4*)((float*)outp + (size_t)node * 4) = o;
        } else {
            float h[15];
#pragma unroll
            for (int j = 0; j < 15; ++j) {
                float bj = (L == 1) ? wl[225 + j] : wl[60 + j];
                h[j] = fmaxf(a[j] * di + bj, 0.f);
            }
            if constexpr (L == 1) {
                float o[16];
                o[15] = 0.f;
#pragma unroll
                for (int j = 0; j < 15; ++j) {
                    float s = 0.f;
#pragma unroll
                    for (int k = 0; k < 15; ++k) s = fmaf(h[k], wl[k * 15 + j], s);
                    o[j] = s * di;
                }
                __half2 ob[8];
#pragma unroll
                for (int j = 0; j < 8; ++j)
                    ob[j] = __floats2half2_rn(o[2 * j], o[2 * j + 1]);
                *(int4*)((__half*)outp + (size_t)node * 16) = *(int4*)&ob[0];
                *(int4*)((__half*)outp + (size_t)node * 16 + 8) = *(int4*)&ob[4];
            } else {
                float o[4];
#pragma unroll
                for (int j = 0; j < 4; ++j) {
                    float s = 0.f;
#pragma unroll
                    for (int k = 0; k < 15; ++k) s = fmaf(h[k], wl[k * 4 + j], s);
                    o[j] = s * di;
                }
                __half2 ob[2];
                ob[0] = __floats2half2_rn(o[0], o[1]);
                ob[1] = __floats2half2_rn(o[2], o[3]);
                *(float2*)((__half*)outp + (size_t)node * 4) = *(float2*)&ob[0];
            }
        }
    }
}

extern "C" void kernel_launch(void* const* d_in, const int* in_sizes, int n_in,
                              void* d_out, int out_size, void* d_ws, size_t ws_size,
                              hipStream_t stream) {
    const float* x  = (const float*)d_in[0];
    const int*   ei = (const int*)d_in[1];
    const float* W1 = (const float*)d_in[3];
    const float* b1 = (const float*)d_in[4];
    const float* W2 = (const float*)d_in[5];
    const float* b2 = (const float*)d_in[6];
    const float* W3 = (const float*)d_in[7];
    const float* b3 = (const float*)d_in[8];
    float* out = (float*)d_out;

    const int N = in_sizes[0] / 15;
    const int E = in_sizes[1] / 2;
    const int* src = ei;
    const int* dst = ei + E;
    const int NBr = (N + BKN - 1) / BKN;   // live buckets (977)
    const int PB  = (NBr + 1) / 2;         // pull blocks (489)

    char* ws = (char*)d_ws;
    auto align = [](size_t v) { return (v + 255) & ~(size_t)255; };
    size_t off = 0;
    uint* rowp8 = (uint*)(ws + off); off += align((size_t)NPART * (1u << 19) * 4);
    float* dis  = (float*)(ws + off); off += align((size_t)N * 4);
    uint* gcur  = (uint*)(ws + off); off += align((size_t)NBMAX * 4);
    uint* bars  = (uint*)(ws + off); off += align((size_t)3 * BAR_LAYER * 4);
    int*  srcS  = (int*)(ws + off);  off += align((size_t)NBMAX * SCAP * 4);
    // slabY: bucketed (71MB) dead after k_csr, overlaid by B'(fp16)+C'(fp16)
    char* slabY = ws + off;
    uint*   bucketed = (uint*)slabY;
    __half* Bp = (__half*)slabY;
    __half* Cp = (__half*)(slabY + align((size_t)(N + 1) * 16 * 2));
    off += align((size_t)NBMAX * BCAP * 4);
    __half* Ap = (__half*)(ws + off);  // (N+1) x 16 fp16

    const int nTiles = (E + PT_TILE - 1) / PT_TILE;
    const int nbN = (N + 255) / 256;

    // CSR build (partition-major rows, fixed slabs)
    k_init<<<1, 1024, 0, stream>>>(gcur, bars);
    k_part<<<nTiles, PT_THREADS, 0, stream>>>(src, dst, E, gcur, bucketed);
    k_csr<<<NBr, 512, 0, stream>>>(bucketed, gcur, rowp8, dis, srcS, N);
    // bucketed dead -> slabY becomes B'/C'

    k_lin_first<<<nbN, 256, 0, stream>>>(x, W1, dis, Ap, N);
    // sentinel zero-rows (row N) for pad gathers
    hipMemsetAsync(Ap + (size_t)N * 16, 0, 16 * 2, stream);
    hipMemsetAsync(Bp + (size_t)N * 16, 0, 16 * 2, stream);
    hipMemsetAsync(Cp + (size_t)N * 4, 0, 4 * 2, stream);

    k_pull_res<1><<<PB, 512, 0, stream>>>(Ap, srcS, rowp8, dis, W2, b1, Bp,
                                          bars + 0 * BAR_LAYER, PB, N);
    k_pull_res<2><<<PB, 512, 0, stream>>>(Bp, srcS, rowp8, dis, W3, b2, Cp,
                                          bars + 1 * BAR_LAYER, PB, N);
    k_pull_res<3><<<PB, 512, 0, stream>>>(Cp, srcS, rowp8, dis, nullptr, b3, out,
                                          bars + 2 * BAR_LAYER, PB, N);
}

// Round 6
// 867.001 us; speedup vs baseline: 2.4804x; 1.0106x over previous
//
#include <hip/hip_runtime.h>
#include <hip/hip_fp16.h>

// GCN 3-layer forward. R11 = R10 + vectorized row gathers:
//  - table rows loaded as dwordx4 pairs (32B row) / dwordx2 (8B row) instead
//    of 8x/2x dword -> 4x fewer TCP lane-transactions (R10 diagnosis: pulls
//    at 9.6% HBM, 18.5% VALU -> TCP-transaction-bound, ~544 mem instrs/thread)
//  - rowp8 prefetch distance-1 across phases (hides rowp8->srcS->rows chain)
//  - CSR build, softbar, partition-major layout identical to R10
// R10: 876 us total, pull1/2 183 us each, FETCH 121MB (near-compulsory).

typedef unsigned int uint;
typedef unsigned short ushort;
typedef unsigned long long ull;

#define NBMAX 1024        // max buckets (dst >> 9), 512 nodes each
#define BKN 512
#define BCAP 17408        // bucketed slab cap per bucket (mean 16384, +8 sigma)
#define SCAP 24576        // srcS slab cap (mean ~22.4k padded, +16 sigma)
#define PT_THREADS 512
#define PT_TILE 8192      // 16 edges per thread
#define NPART 8           // src partitions (src>>16): 2MB fp16 table slices
#define BAR_STRIDE 528    // uints per barrier row (root + 32 spread counters)
#define BAR_LAYER (7 * BAR_STRIDE)

// ---- init: fixed slab cursors + barrier counters ----
__global__ void k_init(uint* __restrict__ gcur, uint* __restrict__ bars) {
    int t = threadIdx.x;                 // 1024 threads, 1 block
    gcur[t] = (uint)t * BCAP;
    for (int i = t; i < 3 * BAR_LAYER; i += 1024) bars[i] = 0;
}

// ---- LDS-staged partition: edges -> bucketed (packed src | dstLocal<<19) ----
__global__ __launch_bounds__(PT_THREADS) void k_part(const int* __restrict__ src,
                                                     const int* __restrict__ dst, int E,
                                                     uint* __restrict__ gcur,
                                                     uint* __restrict__ bucketed) {
    __shared__ uint stage[PT_TILE];
    __shared__ ushort sbuck[PT_TILE];
    __shared__ uint hist[NBMAX], lofs[NBMAX], base[NBMAX];
    __shared__ uint tsum[PT_THREADS];
    int t = threadIdx.x;
    long long start = (long long)blockIdx.x * PT_TILE;
    int cnt = (int)min((long long)PT_TILE, (long long)E - start);

    hist[2 * t] = 0; hist[2 * t + 1] = 0;
    __syncthreads();
    uint myb[16], myr[16], mys[16];
#pragma unroll
    for (int k = 0; k < 16; ++k) {
        int idx = t + k * PT_THREADS;
        if (idx < cnt) {
            uint d = (uint)dst[start + idx];
            uint s = (uint)src[start + idx];
            uint b = d >> 9;
            myb[k] = b;
            mys[k] = s | ((d & 511u) << 19);
            myr[k] = atomicAdd(&hist[b], 1u);
        }
    }
    __syncthreads();
    uint h0 = hist[2 * t], h1 = hist[2 * t + 1];
    tsum[t] = h0 + h1;
    __syncthreads();
    for (int off = 1; off < PT_THREADS; off <<= 1) {
        uint x = (t >= off) ? tsum[t - off] : 0u;
        __syncthreads();
        tsum[t] += x;
        __syncthreads();
    }
    uint ex = tsum[t] - (h0 + h1);
    lofs[2 * t] = ex;
    lofs[2 * t + 1] = ex + h0;
    if (h0) base[2 * t] = atomicAdd(&gcur[2 * t], h0);
    if (h1) base[2 * t + 1] = atomicAdd(&gcur[2 * t + 1], h1);
    __syncthreads();
#pragma unroll
    for (int k = 0; k < 16; ++k) {
        int idx = t + k * PT_THREADS;
        if (idx < cnt) {
            uint pos = lofs[myb[k]] + myr[k];
            stage[pos] = mys[k];
            sbuck[pos] = (ushort)myb[k];
        }
    }
    __syncthreads();
#pragma unroll
    for (int k = 0; k < 16; ++k) {
        int idx = t + k * PT_THREADS;
        if (idx < cnt) {
            uint b = sbuck[idx];
            uint pos = base[b] + ((uint)idx - lofs[b]);
            if (pos < (uint)(b + 1) * BCAP) bucketed[pos] = stage[idx];  // ~always
        }
    }
}

// ---- per-bucket CSR: counting sort keyed (srcPart*512 + dstLocal), pad-to-4 ----
// rowp8[(p<<19)+node] = (slabStart+segStart) | (cnt<<25); pad slots = sentinel N.
__global__ __launch_bounds__(512) void k_csr(const uint* __restrict__ bucketed,
                                             const uint* __restrict__ gcur,
                                             uint* __restrict__ rowp8,
                                             float* __restrict__ dis,
                                             int* __restrict__ srcS, int N) {
    __shared__ uint c[BKN * NPART];        // counts -> cursors (reused)
    __shared__ uint tsum[512];
    __shared__ __align__(16) int stage[SCAP];
    int b = blockIdx.x, t = threadIdx.x;
    uint beg = (uint)b * BCAP;
    uint end = min(gcur[b], (uint)(b + 1) * BCAP);
    for (int i = t; i < BKN * NPART; i += 512) c[i] = 0;
    __syncthreads();
    for (uint e = beg + t; e < end; e += 512) {
        uint v = bucketed[e];
        uint key = (((v & 0x7ffffu) >> 16) << 9) | (v >> 19);
        atomicAdd(&c[key], 1u);
    }
    __syncthreads();
    // degree -> dis (before counts become cursors)
    {
        int node = (b << 9) + t;
        if (node < N) {
            uint deg = 0;
#pragma unroll
            for (int p = 0; p < NPART; ++p) deg += c[(p << 9) | t];
            dis[node] = rsqrtf((float)(deg + 1u));   // +1 self-loop
        }
    }
    // thread t owns keys 8t..8t+7 (one partition p=t>>6, 8 consecutive locals)
    uint cnt[8], pad[8], ps = 0;
#pragma unroll
    for (int i = 0; i < 8; ++i) {
        cnt[i] = c[t * 8 + i];
        pad[i] = (cnt[i] + 3u) & ~3u;
        ps += pad[i];
    }
    __syncthreads();
    tsum[t] = ps;
    __syncthreads();
    for (int off = 1; off < 512; off <<= 1) {
        uint x = (t >= off) ? tsum[t - off] : 0u;
        __syncthreads();
        tsum[t] += x;
        __syncthreads();
    }
    uint tot = tsum[511];
    uint kb = tsum[t] - ps;
    uint slab = (uint)b * SCAP;
    int p = t >> 6, local0 = (t & 63) << 3;
    uint run = kb;
#pragma unroll
    for (int i = 0; i < 8; ++i) {
        uint st = run;
        rowp8[((uint)p << 19) + (uint)((b << 9) + local0 + i)] =
            (slab + st) | (cnt[i] << 25);
        c[t * 8 + i] = st;                  // cursor, slab-relative
        for (uint q = cnt[i]; q < pad[i]; ++q) {   // sentinel pads (<=3)
            uint idx = st + q;
            if (idx < (uint)SCAP) stage[idx] = N;
            else srcS[slab + idx] = N;      // ~never (spill)
        }
        run += pad[i];
    }
    __syncthreads();
    for (uint e = beg + t; e < end; e += 512) {
        uint v = bucketed[e];
        uint s = v & 0x7ffffu;
        uint key = ((s >> 16) << 9) | (v >> 19);
        uint idx = atomicAdd(&c[key], 1u);
        if (idx < (uint)SCAP) stage[idx] = (int)s;
        else srcS[slab + idx] = (int)s;     // ~never (spill)
    }
    __syncthreads();
    uint capped = min(tot, (uint)SCAP);
    uint cap4 = capped & ~3u;
    for (uint i = t * 4; i < cap4; i += 512 * 4)
        *(int4*)(srcS + slab + i) = *(const int4*)(stage + i);
    if (t < (int)(capped & 3u)) srcS[slab + cap4 + t] = stage[cap4 + t];
}

// ---- layer-1: A'[i,0:15] = (x[i,:]@W1) * dis[i] -> fp16, A'[i,15]=0 ----
__global__ void k_lin_first(const float* __restrict__ x, const float* __restrict__ W,
                            const float* __restrict__ dis, __half* __restrict__ A, int N) {
    int i = blockIdx.x * blockDim.x + threadIdx.x;
    if (i >= N) return;
    float in[15];
#pragma unroll
    for (int j = 0; j < 15; ++j) in[j] = x[i * 15 + j];
    float di = dis[i];
#pragma unroll
    for (int o = 0; o < 15; ++o) {
        float acc = 0.f;
#pragma unroll
        for (int j = 0; j < 15; ++j) acc = fmaf(in[j], W[j * 15 + o], acc);
        A[i * 16 + o] = __float2half(acc * di);
    }
    A[i * 16 + 15] = __float2half(0.f);
}

// ---- soft global barrier: locality pacing only (no correctness dependence) ----
__device__ __forceinline__ void softbar(uint* __restrict__ bars, int phase, int nblk) {
    __syncthreads();
    if (threadIdx.x == 0) {
        uint* row = bars + phase * BAR_STRIDE;
        uint ngroups = ((uint)nblk + 31u) >> 5;
        uint g = (uint)blockIdx.x >> 5;
        uint gsz = min(32u, (uint)nblk - g * 32u);
        uint prev = atomicAdd(&row[16 + g * 16], 1u);   // spread counters, own line
        if (prev + 1u == gsz) atomicAdd(&row[0], 1u);
        int spins = 0;
        while (spins < 2000) {
            uint v = __hip_atomic_load(&row[0], __ATOMIC_RELAXED,
                                       __HIP_MEMORY_SCOPE_AGENT);
            if (v >= ngroups) break;
            __builtin_amdgcn_s_sleep(8);
            ++spins;
        }
    }
    __syncthreads();
}

template <int TW>
__device__ __forceinline__ void load_row(const __half* __restrict__ tab, int node,
                                         float (&acc)[TW]) {
    if constexpr (TW == 16) {
        int4 w0 = *(const int4*)(tab + (size_t)node * 16);
        int4 w1 = *(const int4*)(tab + (size_t)node * 16 + 8);
        const __half2* h0 = (const __half2*)&w0;
        const __half2* h1 = (const __half2*)&w1;
#pragma unroll
        for (int u = 0; u < 4; ++u) {
            float2 f0 = __half22float2(h0[u]);
            float2 f1 = __half22float2(h1[u]);
            acc[2 * u] = f0.x;
            acc[2 * u + 1] = f0.y;
            acc[8 + 2 * u] = f1.x;
            acc[8 + 2 * u + 1] = f1.y;
        }
    } else {
        int2 w = *(const int2*)(tab + (size_t)node * 4);
        const __half2* h = (const __half2*)&w;
        float2 f0 = __half22float2(h[0]);
        float2 f1 = __half22float2(h[1]);
        acc[0] = f0.x; acc[1] = f0.y; acc[2] = f1.x; acc[3] = f1.y;
    }
}

// vectorized gather: 32B rows as 2x dwordx4, 8B rows as dwordx2
template <int TW>
__device__ __forceinline__ void gather_seg(const __half* __restrict__ tab,
                                           const int* __restrict__ srcS,
                                           uint rv, float (&acc)[TW]) {
    uint cnt = rv >> 25;
    if (!cnt) return;
    uint e = rv & 0x1ffffffu;
    uint end4 = e + ((cnt + 3u) & ~3u);
    for (; e < end4; e += 4) {
        int4 s4 = *(const int4*)(srcS + e);     // 16B-aligned segment
        if constexpr (TW == 16) {
            const int4* p0 = (const int4*)(tab + (size_t)s4.x * 16);
            const int4* p1 = (const int4*)(tab + (size_t)s4.y * 16);
            const int4* p2 = (const int4*)(tab + (size_t)s4.z * 16);
            const int4* p3 = (const int4*)(tab + (size_t)s4.w * 16);
            int4 r[8];
            r[0] = p0[0]; r[1] = p1[0]; r[2] = p2[0]; r[3] = p3[0];
            r[4] = p0[1]; r[5] = p1[1]; r[6] = p2[1]; r[7] = p3[1];
#pragma unroll
            for (int q = 0; q < 8; ++q) {
                const __half2* h2 = (const __half2*)&r[q];
                int base = (q >> 2) * 8;        // r[0..3] -> lo half, r[4..7] -> hi
#pragma unroll
                for (int u = 0; u < 4; ++u) {
                    float2 f = __half22float2(h2[u]);
                    acc[base + 2 * u] += f.x;
                    acc[base + 2 * u + 1] += f.y;
                }
            }
        } else {                                // TW == 4
            int2 r0 = *(const int2*)(tab + (size_t)s4.x * 4);
            int2 r1 = *(const int2*)(tab + (size_t)s4.y * 4);
            int2 r2 = *(const int2*)(tab + (size_t)s4.z * 4);
            int2 r3 = *(const int2*)(tab + (size_t)s4.w * 4);
            const __half2* h0 = (const __half2*)&r0;
            const __half2* h1 = (const __half2*)&r1;
            const __half2* h2 = (const __half2*)&r2;
            const __half2* h3 = (const __half2*)&r3;
#pragma unroll
            for (int u = 0; u < 2; ++u) {
                float2 f0 = __half22float2(h0[u]);
                float2 f1 = __half22float2(h1[u]);
                float2 f2 = __half22float2(h2[u]);
                float2 f3 = __half22float2(h3[u]);
                acc[2 * u] += (f0.x + f1.x) + (f2.x + f3.x);
                acc[2 * u + 1] += (f0.y + f1.y) + (f2.y + f3.y);
            }
        }
    }
}

// ---- resident phased pull: thread owns 2 nodes, register acc, 8 phases ----
// L=1: Ap->relu@W2->Bp  L=2: Bp->relu@W3->Cp  L=3: Cp->out fp32
template <int L>
__global__ __launch_bounds__(512, 4) void k_pull_res(
    const __half* __restrict__ tab, const int* __restrict__ srcS,
    const uint* __restrict__ rowp8, const float* __restrict__ dis,
    const float* __restrict__ Wm, const float* __restrict__ bias,
    void* __restrict__ outp, uint* __restrict__ bars, int nblk, int N) {
    constexpr int TW = (L == 3) ? 4 : 16;
    __shared__ float wl[240];
    int t = threadIdx.x;
    int n0 = (blockIdx.x << 10) + t;
    int n1 = n0 + 512;
    if constexpr (L == 1) {
        for (int i = t; i < 225; i += 512) wl[i] = Wm[i];
        if (t < 15) wl[225 + t] = bias[t];
    }
    if constexpr (L == 2) {
        for (int i = t; i < 60; i += 512) wl[i] = Wm[i];
        if (t < 15) wl[60 + t] = bias[t];
    }
    if constexpr (L == 3) {
        if (t < 4) wl[t] = bias[t];
    }
    __syncthreads();
    bool v0 = n0 < N, v1 = n1 < N;
    float a0[TW], a1[TW];
    if (v0) load_row<TW>(tab, n0, a0);
    if (v1) load_row<TW>(tab, n1, a1);
    uint rv0 = v0 ? rowp8[(uint)n0] : 0u;      // phase-0 descriptors
    uint rv1 = v1 ? rowp8[(uint)n1] : 0u;
    for (int p = 0; p < NPART; ++p) {
        uint nv0 = 0u, nv1 = 0u;
        if (p < NPART - 1) {                   // prefetch next phase descriptors
            uint pb = (uint)(p + 1) << 19;
            if (v0) nv0 = rowp8[pb + (uint)n0];
            if (v1) nv1 = rowp8[pb + (uint)n1];
        }
        if (v0) gather_seg<TW>(tab, srcS, rv0, a0);
        if (v1) gather_seg<TW>(tab, srcS, rv1, a1);
        if (p < NPART - 1) softbar(bars, p, nblk);
        rv0 = nv0; rv1 = nv1;
    }
    // epilogue (per node, all-register MLP)
#pragma unroll
    for (int nn = 0; nn < 2; ++nn) {
        int node = nn ? n1 : n0;
        if (node >= N) continue;
        float* a = nn ? a1 : a0;
        float di = dis[node];
        if constexpr (L == 3) {
            float4 o;
            o.x = a[0] * di + wl[0];
            o.y = a[1] * di + wl[1];
            o.z = a[2] * di + wl[2];
            o.w = a[3] * di + wl[3];
            *(float4*)((float*)outp + (size_t)node * 4) = o;
        } else {
            float h[15];
#pragma unroll
            for (int j = 0; j < 15; ++j) {
                float bj = (L == 1) ? wl[225 + j] : wl[60 + j];
                h[j] = fmaxf(a[j] * di + bj, 0.f);
            }
            if constexpr (L == 1) {
                float o[16];
                o[15] = 0.f;
#pragma unroll
                for (int j = 0; j < 15; ++j) {
                    float s = 0.f;
#pragma unroll
                    for (int k = 0; k < 15; ++k) s = fmaf(h[k], wl[k * 15 + j], s);
                    o[j] = s * di;
                }
                __half2 ob[8];
#pragma unroll
                for (int j = 0; j < 8; ++j)
                    ob[j] = __floats2half2_rn(o[2 * j], o[2 * j + 1]);
                *(int4*)((__half*)outp + (size_t)node * 16) = *(int4*)&ob[0];
                *(int4*)((__half*)outp + (size_t)node * 16 + 8) = *(int4*)&ob[4];
            } else {
                float o[4];
#pragma unroll
                for (int j = 0; j < 4; ++j) {
                    float s = 0.f;
#pragma unroll
                    for (int k = 0; k < 15; ++k) s = fmaf(h[k], wl[k * 4 + j], s);
                    o[j] = s * di;
                }
                __half2 ob[2];
                ob[0] = __floats2half2_rn(o[0], o[1]);
                ob[1] = __floats2half2_rn(o[2], o[3]);
                *(float2*)((__half*)outp + (size_t)node * 4) = *(float2*)&ob[0];
            }
        }
    }
}

extern "C" void kernel_launch(void* const* d_in, const int* in_sizes, int n_in,
                              void* d_out, int out_size, void* d_ws, size_t ws_size,
                              hipStream_t stream) {
    const float* x  = (const float*)d_in[0];
    const int*   ei = (const int*)d_in[1];
    const float* W1 = (const float*)d_in[3];
    const float* b1 = (const float*)d_in[4];
    const float* W2 = (const float*)d_in[5];
    const float* b2 = (const float*)d_in[6];
    const float* W3 = (const float*)d_in[7];
    const float* b3 = (const float*)d_in[8];
    float* out = (float*)d_out;

    const int N = in_sizes[0] / 15;
    const int E = in_sizes[1] / 2;
    const int* src = ei;
    const int* dst = ei + E;
    const int NBr = (N + BKN - 1) / BKN;   // live buckets (977)
    const int PB  = (NBr + 1) / 2;         // pull blocks (489)

    char* ws = (char*)d_ws;
    auto align = [](size_t v) { return (v + 255) & ~(size_t)255; };
    size_t off = 0;
    uint* rowp8 = (uint*)(ws + off); off += align((size_t)NPART * (1u << 19) * 4);
    float* dis  = (float*)(ws + off); off += align((size_t)N * 4);
    uint* gcur  = (uint*)(ws + off); off += align((size_t)NBMAX * 4);
    uint* bars  = (uint*)(ws + off); off += align((size_t)3 * BAR_LAYER * 4);
    int*  srcS  = (int*)(ws + off);  off += align((size_t)NBMAX * SCAP * 4);
    // slabY: bucketed (71MB) dead after k_csr, overlaid by B'(fp16)+C'(fp16)
    char* slabY = ws + off;
    uint*   bucketed = (uint*)slabY;
    __half* Bp = (__half*)slabY;
    __half* Cp = (__half*)(slabY + align((size_t)(N + 1) * 16 * 2));
    off += align((size_t)NBMAX * BCAP * 4);
    __half* Ap = (__half*)(ws + off);  // (N+1) x 16 fp16

    const int nTiles = (E + PT_TILE - 1) / PT_TILE;
    const int nbN = (N + 255) / 256;

    // CSR build (partition-major rows, fixed slabs)
    k_init<<<1, 1024, 0, stream>>>(gcur, bars);
    k_part<<<nTiles, PT_THREADS, 0, stream>>>(src, dst, E, gcur, bucketed);
    k_csr<<<NBr, 512, 0, stream>>>(bucketed, gcur, rowp8, dis, srcS, N);
    // bucketed dead -> slabY becomes B'/C'

    k_lin_first<<<nbN, 256, 0, stream>>>(x, W1, dis, Ap, N);
    // sentinel zero-rows (row N) for pad gathers
    hipMemsetAsync(Ap + (size_t)N * 16, 0, 16 * 2, stream);
    hipMemsetAsync(Bp + (size_t)N * 16, 0, 16 * 2, stream);
    hipMemsetAsync(Cp + (size_t)N * 4, 0, 4 * 2, stream);

    k_pull_res<1><<<PB, 512, 0, stream>>>(Ap, srcS, rowp8, dis, W2, b1, Bp,
                                          bars + 0 * BAR_LAYER, PB, N);
    k_pull_res<2><<<PB, 512, 0, stream>>>(Bp, srcS, rowp8, dis, W3, b2, Cp,
                                          bars + 1 * BAR_LAYER, PB, N);
    k_pull_res<3><<<PB, 512, 0, stream>>>(Cp, srcS, rowp8, dis, nullptr, b3, out,
                                          bars + 2 * BAR_LAYER, PB, N);
}